// Round 6
// baseline (256.673 us; speedup 1.0000x reference)
//
#include <hip/hip_runtime.h>

namespace {

typedef float v2f __attribute__((ext_vector_type(2)));

constexpr int kW = 640;
constexpr int kN = 230400;            // 360*640
constexpr unsigned kSpan = 230400u;
constexpr int kB = 512;               // blocks; 512*450 = kN
constexpr int kPPB = 450;             // points per block
constexpr unsigned kPoison = 0xAAAAAAAAu;

// ws slot offsets (bytes); ws is poisoned 0xAA before every run
constexpr size_t kOffMaxv   = 0;      // u64: f32 bits of maxv
constexpr size_t kOffLoss17 = 8;      // u64: double bits of loss17
constexpr size_t kOffC1     = 128;    // stats arrival counter
constexpr size_t kOffF1     = 192;    // flag: planes/maxv ready (!= poison)
constexpr size_t kOffC2     = 256;    // count arrival counter
constexpr size_t kOffC2b    = 320;    // select-done counter
constexpr size_t kOffF2     = 384;    // flag: final selkey (!= poison)
constexpr size_t kOffC3     = 448;    // zc arrival counter
constexpr size_t kOffSel    = 512;    // selkey atomicMax target (init 0 by stats tail)
constexpr size_t kOffPlanes = 1024;                    // 1024*16 = 16384
constexpr size_t kOffSP     = 1024 + 16384;            // 512*48  = 24576
constexpr size_t kOffZP     = kOffSP + 24576;          // 512*24  = 12288
constexpr size_t kOffPart   = 131072;                  // 512*256*8 = 1 MB

__device__ __forceinline__ void ast64(unsigned long long* p, unsigned long long v) {
  __hip_atomic_store(p, v, __ATOMIC_RELAXED, __HIP_MEMORY_SCOPE_AGENT);
}
__device__ __forceinline__ unsigned long long ald64(const unsigned long long* p) {
  return __hip_atomic_load(p, __ATOMIC_RELAXED, __HIP_MEMORY_SCOPE_AGENT);
}
__device__ __forceinline__ void ast32(unsigned* p, unsigned v) {
  __hip_atomic_store(p, v, __ATOMIC_RELAXED, __HIP_MEMORY_SCOPE_AGENT);
}
__device__ __forceinline__ unsigned rotl32(unsigned v, int r) {
  return (v << r) | (v >> (32 - r));
}

// Threefry-2x32, 20 rounds, key = (0, 42)  [jax.random.key(42)]
__device__ __forceinline__ void threefry(unsigned c0, unsigned c1,
                                         unsigned& o0, unsigned& o1) {
  const unsigned ks0 = 0u, ks1 = 42u, ks2 = 0x1BD11BDAu ^ 0u ^ 42u;
  unsigned x0 = c0 + ks0, x1 = c1 + ks1;
#define TFR(r) { x0 += x1; x1 = rotl32(x1, (r)); x1 ^= x0; }
  TFR(13) TFR(15) TFR(26) TFR(6)
  x0 += ks1; x1 += ks2 + 1u;
  TFR(17) TFR(29) TFR(16) TFR(24)
  x0 += ks2; x1 += ks0 + 2u;
  TFR(13) TFR(15) TFR(26) TFR(6)
  x0 += ks0; x1 += ks1 + 3u;
  TFR(17) TFR(29) TFR(16) TFR(24)
  x0 += ks1; x1 += ks2 + 4u;
  TFR(13) TFR(15) TFR(26) TFR(6)
  x0 += ks2; x1 += ks0 + 5u;
#undef TFR
  o0 = x0; o1 = x1;
}

__device__ __forceinline__ void pix_coords(float d, int row, int col, bool& valid,
                                           float& x, float& y, float& z) {
  valid = (d > 0.0f) && (d < 65535.0f);
  float z0 = d / 1000.0f;
  float x0 = z0 * ((float)col - 334.081f) / 460.585f;
  float y0 = z0 * ((float)row - 169.808f) / 460.268f;
  x = x0 * 1000.0f;
  y = y0 * 1000.0f;
  z = z0 * 1000.0f;
  if (x == 0.0f) x = 1e-7f;
  if (y == 0.0f) y = 1e-7f;
  if (z == 0.0f) z = 1e-7f;
}

// normalized point — identical expression wherever used (bitwise mask consistency)
__device__ __forceinline__ void make_pt(float d, int row, int col, float maxv,
                                        float& x, float& y, float& z) {
  bool v; float a, b, c;
  pix_coords(d, row, col, v, a, b, c);
  x = (v ? a : 0.f) / maxv;
  y = (v ? b : 0.f) / maxv;
  z = (v ? c : 0.f) / maxv;
}

__device__ __forceinline__ float get_thresh(int ep) {
  return (float)fmax(0.025 - 0.001 * (double)ep, 0.005);
}

// ====================== the whole pipeline, one cooperative kernel ======================
__global__ __launch_bounds__(256, 2) void k_all(const float* __restrict__ fake,
                                                const float* __restrict__ real,
                                                const int* __restrict__ epoch,
                                                float* __restrict__ out,
                                                char* __restrict__ ws) {
  unsigned long long* wMaxv = (unsigned long long*)(ws + kOffMaxv);
  unsigned long long* wL17 = (unsigned long long*)(ws + kOffLoss17);
  unsigned* wC1 = (unsigned*)(ws + kOffC1);
  unsigned* wF1 = (unsigned*)(ws + kOffF1);
  unsigned* wC2 = (unsigned*)(ws + kOffC2);
  unsigned* wC2b = (unsigned*)(ws + kOffC2b);
  unsigned* wF2 = (unsigned*)(ws + kOffF2);
  unsigned* wC3 = (unsigned*)(ws + kOffC3);
  unsigned* wSel = (unsigned*)(ws + kOffSel);
  unsigned long long* planes = (unsigned long long*)(ws + kOffPlanes); // 2 u64 per plane
  unsigned long long* sp = (unsigned long long*)(ws + kOffSP);
  unsigned long long* zp = (unsigned long long*)(ws + kOffZP);
  unsigned long long* part = (unsigned long long*)(ws + kOffPart);

  const int b = blockIdx.x, t = threadIdx.x;
  const int lane = t & 63, wid = t >> 6;
  const float th = get_thresh(*epoch);

  __shared__ float4 sPts[kPPB];
  __shared__ uint4 sAcc[16][16];
  __shared__ double sD0[4], sD1[4], sD2[4], sD3[4];
  __shared__ int sI0[4];
  __shared__ float sF0[4], sF1s[4];
  __shared__ unsigned sU;

  // ---------------- Phase 1: stats over my 450 points (<=2 per thread) ----------------
  float p0x, p0y, p0z, p1x = 0.f, p1y = 0.f, p1z = 0.f;   // masked raw fake coords
  const bool has2 = (t < kPPB - 256);                     // t < 194
  {
    double dx2 = 0, dy2 = 0, dz2 = 0, dl2 = 0; int cc = 0; float mx = 0.f;
    {
      int i = b * kPPB + t;
      int row = i / kW, col = i - row * kW;
      bool vr, vf; float rx, ry, rz, fx, fy, fz;
      pix_coords(real[i], row, col, vr, rx, ry, rz);
      pix_coords(fake[i], row, col, vf, fx, fy, fz);
      p0x = vf ? fx : 0.f; p0y = vf ? fy : 0.f; p0z = vf ? fz : 0.f;
      if (vr && vf) {
        float ddx = rx - fx, ddy = ry - fy, ddz = rz - fz;
        dx2 += (double)ddx * (double)ddx;
        dy2 += (double)ddy * (double)ddy;
        dz2 += (double)ddz * (double)ddz;
        double dl = log(fabs((double)rz)) - log(fabs((double)fz));
        dl2 += dl * dl;
        cc++;
      }
      if (vf) mx = fmaxf(mx, fmaxf(fmaxf(fx, fy), fz));
    }
    if (has2) {
      int i = b * kPPB + t + 256;
      int row = i / kW, col = i - row * kW;
      bool vr, vf; float rx, ry, rz, fx, fy, fz;
      pix_coords(real[i], row, col, vr, rx, ry, rz);
      pix_coords(fake[i], row, col, vf, fx, fy, fz);
      p1x = vf ? fx : 0.f; p1y = vf ? fy : 0.f; p1z = vf ? fz : 0.f;
      if (vr && vf) {
        float ddx = rx - fx, ddy = ry - fy, ddz = rz - fz;
        dx2 += (double)ddx * (double)ddx;
        dy2 += (double)ddy * (double)ddy;
        dz2 += (double)ddz * (double)ddz;
        double dl = log(fabs((double)rz)) - log(fabs((double)fz));
        dl2 += dl * dl;
        cc++;
      }
      if (vf) mx = fmaxf(mx, fmaxf(fmaxf(fx, fy), fz));
    }
    for (int o = 32; o; o >>= 1) {
      dx2 += __shfl_down(dx2, o); dy2 += __shfl_down(dy2, o);
      dz2 += __shfl_down(dz2, o); dl2 += __shfl_down(dl2, o);
      cc += __shfl_down(cc, o);
      mx = fmaxf(mx, __shfl_down(mx, o));
    }
    if (lane == 0) { sD0[wid]=dx2; sD1[wid]=dy2; sD2[wid]=dz2; sD3[wid]=dl2;
                     sI0[wid]=cc; sF0[wid]=mx; }
    __syncthreads();
    if (t == 0) {
      unsigned long long* e = sp + (size_t)b * 6;
      ast64(e + 0, __double_as_longlong(sD0[0]+sD0[1]+sD0[2]+sD0[3]));
      ast64(e + 1, __double_as_longlong(sD1[0]+sD1[1]+sD1[2]+sD1[3]));
      ast64(e + 2, __double_as_longlong(sD2[0]+sD2[1]+sD2[2]+sD2[3]));
      ast64(e + 3, __double_as_longlong(sD3[0]+sD3[1]+sD3[2]+sD3[3]));
      ast64(e + 4, (unsigned long long)(sI0[0]+sI0[1]+sI0[2]+sI0[3]));
      float bm = fmaxf(fmaxf(sF0[0], sF0[1]), fmaxf(sF0[2], sF0[3]));
      ast64(e + 5, (unsigned long long)__float_as_uint(bm));
    }
  }
  __syncthreads();   // compiler drains vmcnt before barrier -> stores globally performed
  if (t == 0)
    sU = __hip_atomic_fetch_add(wC1, 1u, __ATOMIC_ACQ_REL, __HIP_MEMORY_SCOPE_AGENT);
  __syncthreads();

  if (sU == kPoison + (unsigned)(kB - 1)) {
    // ---- stats tail: reduce partials, scalars, build planes, publish F1 ----
    double gx = 0, gy = 0, gz = 0, gl = 0; int gc = 0; float gm = 0.f;
    for (int r = t; r < kB; r += 256) {
      const unsigned long long* e = sp + (size_t)r * 6;
      gx += __longlong_as_double(ald64(e + 0));
      gy += __longlong_as_double(ald64(e + 1));
      gz += __longlong_as_double(ald64(e + 2));
      gl += __longlong_as_double(ald64(e + 3));
      gc += (int)ald64(e + 4);
      gm = fmaxf(gm, __uint_as_float((unsigned)ald64(e + 5)));
    }
    for (int o = 32; o; o >>= 1) {
      gx += __shfl_down(gx, o); gy += __shfl_down(gy, o);
      gz += __shfl_down(gz, o); gl += __shfl_down(gl, o);
      gc += __shfl_down(gc, o);
      gm = fmaxf(gm, __shfl_down(gm, o));
    }
    if (lane == 0) { sD0[wid]=gx; sD1[wid]=gy; sD2[wid]=gz; sD3[wid]=gl;
                     sI0[wid]=gc; sF0[wid]=gm; }
    __syncthreads();
    __shared__ float sMaxv;
    if (t == 0) {
      double SX = sD0[0]+sD0[1]+sD0[2]+sD0[3];
      double SY = sD1[0]+sD1[1]+sD1[2]+sD1[3];
      double SZ = sD2[0]+sD2[1]+sD2[2]+sD2[3];
      double SL = sD3[0]+sD3[1]+sD3[2]+sD3[3];
      int CN = sI0[0]+sI0[1]+sI0[2]+sI0[3];
      float MX = fmaxf(fmaxf(sF0[0], sF0[1]), fmaxf(sF0[2], sF0[3]));
      double cntd = (CN > 0) ? (double)CN : 1.0;
      double lossX = sqrt(SX / cntd);
      double lossY = sqrt(SY / cntd);
      double lossZ = sqrt(SZ / cntd);
      double rmse_log = 10000.0 * sqrt(SL / cntd);
      double loss17 = rmse_log * fabs(10.0 * (3.0 - exp(lossX) - exp(lossY) - exp(lossZ)));
      out[0] = (float)rmse_log;
      out[1] = (float)lossX;
      out[2] = (float)lossY;
      out[3] = (float)lossZ;
      out[5] = (float)loss17;
      ast64(wMaxv, (unsigned long long)__float_as_uint(MX));
      ast64(wL17, __double_as_longlong(loss17));
      ast32(wSel, 0u);                       // init atomicMax target
      sMaxv = MX;
    }
    __syncthreads();
    {
      float maxv = sMaxv;
#pragma unroll
      for (int j = 0; j < 4; j++) {
        int pid = t * 4 + j;                 // 0..1023
        float4 pl;
        if (pid < 1000) {
          float px[3], py[3], pz[3];
#pragma unroll
          for (int v = 0; v < 3; v++) {
            unsigned p = 3u * (unsigned)pid + (unsigned)v;
            unsigned o0, o1;
            threefry(p, p + 3000u, o0, o1);  // JAX randint: multiplier wraps to 0 => o1 % span
            unsigned idx = o1 % kSpan;
            int row = (int)(idx / kW), col = (int)idx - row * kW;
            make_pt(fake[idx], row, col, maxv, px[v], py[v], pz[v]);
          }
          float ax = px[1]-px[0], ay = py[1]-py[0], az = pz[1]-pz[0];
          float bx = px[2]-px[0], by = py[2]-py[0], bz = pz[2]-pz[0];
          float nx = ay*bz - az*by;
          float ny = az*bx - ax*bz;
          float nz = ax*by - ay*bx;
          float nn = sqrtf(nx*nx + ny*ny + nz*nz);
          nx /= nn; ny /= nn; nz /= nn;
          float kk = -(nx*px[1] + ny*py[1] + nz*pz[1]);
          pl = make_float4(nx, ny, nz, kk);
        } else {
          pl = make_float4(0.f, 0.f, 0.f, 3e38f);     // dummy: never an inlier
        }
        ast64(&planes[2*pid],   (unsigned long long)__float_as_uint(pl.x) |
                               ((unsigned long long)__float_as_uint(pl.y) << 32));
        ast64(&planes[2*pid+1], (unsigned long long)__float_as_uint(pl.z) |
                               ((unsigned long long)__float_as_uint(pl.w) << 32));
      }
    }
    __syncthreads();   // drain vmcnt: plane stores globally performed
    if (t == 0)
      __hip_atomic_store(wF1, 1u, __ATOMIC_RELEASE, __HIP_MEMORY_SCOPE_AGENT);
  } else {
    if (t == 0) {
      while (__hip_atomic_load(wF1, __ATOMIC_ACQUIRE, __HIP_MEMORY_SCOPE_AGENT) == kPoison)
        __builtin_amdgcn_s_sleep(8);
    }
    __syncthreads();
  }

  // ---------------- Phase 2: normalize pts into LDS; count 4 planes/thread ----------------
  const float maxv = __uint_as_float((unsigned)ald64(wMaxv));
  sPts[t] = make_float4(p0x / maxv, p0y / maxv, p0z / maxv, 0.f);
  if (has2) sPts[t + 256] = make_float4(p1x / maxv, p1y / maxv, p1z / maxv, 0.f);

  unsigned long long pq0 = ald64(&planes[2*(t*4+0)]), pq1 = ald64(&planes[2*(t*4+0)+1]);
  unsigned long long pq2 = ald64(&planes[2*(t*4+1)]), pq3 = ald64(&planes[2*(t*4+1)+1]);
  unsigned long long pq4 = ald64(&planes[2*(t*4+2)]), pq5 = ald64(&planes[2*(t*4+2)+1]);
  unsigned long long pq6 = ald64(&planes[2*(t*4+3)]), pq7 = ald64(&planes[2*(t*4+3)+1]);
  v2f Ax = {__uint_as_float((unsigned)pq0), __uint_as_float((unsigned)pq2)};
  v2f Ay = {__uint_as_float((unsigned)(pq0>>32)), __uint_as_float((unsigned)(pq2>>32))};
  v2f Az = {__uint_as_float((unsigned)pq1), __uint_as_float((unsigned)pq3)};
  v2f Aw = {__uint_as_float((unsigned)(pq1>>32)), __uint_as_float((unsigned)(pq3>>32))};
  v2f Bx = {__uint_as_float((unsigned)pq4), __uint_as_float((unsigned)pq6)};
  v2f By = {__uint_as_float((unsigned)(pq4>>32)), __uint_as_float((unsigned)(pq6>>32))};
  v2f Bz = {__uint_as_float((unsigned)pq5), __uint_as_float((unsigned)pq7)};
  v2f Bw = {__uint_as_float((unsigned)(pq5>>32)), __uint_as_float((unsigned)(pq7>>32))};
  __syncthreads();

  unsigned c0 = 0, c1 = 0, c2 = 0, c3 = 0;
#pragma unroll 6
  for (int s = 0; s < kPPB; ++s) {
    float4 q = sPts[s];                    // broadcast ds_read_b128
    v2f qx = {q.x, q.x}, qy = {q.y, q.y}, qz = {q.z, q.z};
    // per-half chain == fmaf(qx,a,fmaf(qy,b,fmaf(qz,c,d))) — matches phase-3 scalar chain
    v2f dA = __builtin_elementwise_fma(qx, Ax,
             __builtin_elementwise_fma(qy, Ay,
             __builtin_elementwise_fma(qz, Az, Aw)));
    v2f dB = __builtin_elementwise_fma(qx, Bx,
             __builtin_elementwise_fma(qy, By,
             __builtin_elementwise_fma(qz, Bz, Bw)));
    c0 += (fabsf(dA.x) <= th) ? 1u : 0u;
    c1 += (fabsf(dA.y) <= th) ? 1u : 0u;
    c2 += (fabsf(dB.x) <= th) ? 1u : 0u;
    c3 += (fabsf(dB.y) <= th) ? 1u : 0u;
  }
  // counts <= 450 fit u16; one packed store per thread
  ast64(&part[(size_t)b * 256 + t],
        ((unsigned long long)(c0 | (c1 << 16))) |
        ((unsigned long long)(c2 | (c3 << 16)) << 32));
  __syncthreads();   // drain vmcnt
  if (t == 0)
    sU = __hip_atomic_fetch_add(wC2, 1u, __ATOMIC_ACQ_REL, __HIP_MEMORY_SCOPE_AGENT);
  __syncthreads();
  unsigned ret2 = sU;

  if (ret2 >= kPoison + (unsigned)(kB - 16)) {
    // ---- distributed select: last 16 arrivals, 16 owner-threads (64 planes) each ----
    int r = (int)(ret2 - (kPoison + (unsigned)(kB - 16)));   // 0..15
    if (t == 0) {
      while (__hip_atomic_load(wC2, __ATOMIC_ACQUIRE, __HIP_MEMORY_SCOPE_AGENT)
             != kPoison + (unsigned)kB)
        __builtin_amdgcn_s_sleep(2);
    }
    __syncthreads();
    int owner = r * 16 + (t & 15);        // owner-thread column 0..255
    int chunk = t >> 4;                   // 16 chunks x 32 rows
    unsigned s0 = 0, s1 = 0, s2 = 0, s3 = 0;
    for (int row = chunk * 32; row < chunk * 32 + 32; ++row) {
      unsigned long long v = ald64(&part[(size_t)row * 256 + owner]);
      s0 += (unsigned)(v & 0xFFFFu);
      s1 += (unsigned)((v >> 16) & 0xFFFFu);
      s2 += (unsigned)((v >> 32) & 0xFFFFu);
      s3 += (unsigned)(v >> 48);
    }
    sAcc[t & 15][chunk] = make_uint4(s0, s1, s2, s3);
    __syncthreads();
    unsigned mykey = 0u;
    if (t < 16) {
      unsigned t0 = 0, t1 = 0, t2 = 0, t3 = 0;
      for (int j = 0; j < 16; ++j) {
        uint4 v = sAcc[t][j];
        t0 += v.x; t1 += v.y; t2 += v.z; t3 += v.w;
      }
      unsigned tot[4] = {t0, t1, t2, t3};
      int pbase = (r * 16 + t) * 4;
#pragma unroll
      for (int k = 0; k < 4; ++k) {
        int p = pbase + k;
        int score = ((int)tot[k] > 5000) ? (int)tot[k] : -1;   // MIN_POINTS, strict >
        unsigned key = ((unsigned)(score + 2) << 10) | (unsigned)(1023 - p);
        mykey = key > mykey ? key : mykey;
      }
    }
    for (int o = 32; o; o >>= 1) {
      unsigned other = __shfl_down(mykey, o);
      mykey = other > mykey ? other : mykey;
    }
    if (t == 0) {
      atomicMax(wSel, mykey);
      unsigned d = __hip_atomic_fetch_add(wC2b, 1u, __ATOMIC_ACQ_REL,
                                          __HIP_MEMORY_SCOPE_AGENT);
      if (d == kPoison + 15u) {
        unsigned fin = __hip_atomic_load(wSel, __ATOMIC_RELAXED, __HIP_MEMORY_SCOPE_AGENT);
        __hip_atomic_store(wF2, fin, __ATOMIC_RELEASE, __HIP_MEMORY_SCOPE_AGENT);
      }
    }
  }
  // all blocks wait for the final selection
  if (t == 0) {
    unsigned v;
    while ((v = __hip_atomic_load(wF2, __ATOMIC_ACQUIRE, __HIP_MEMORY_SCOPE_AGENT))
           == kPoison)
      __builtin_amdgcn_s_sleep(4);
    sU = v;
  }
  __syncthreads();

  // ---------------- Phase 3: zc over my 450 LDS points (bit-identical inputs) ----------------
  {
    int best = 1023 - (int)(sU & 1023u);
    unsigned long long b0 = ald64(&planes[2*best]), b1 = ald64(&planes[2*best+1]);
    const float a = __uint_as_float((unsigned)b0);
    const float bb = __uint_as_float((unsigned)(b0 >> 32));
    const float c = __uint_as_float((unsigned)b1);
    const float d = __uint_as_float((unsigned)(b1 >> 32));
    float n2 = a * a + bb * bb + c * c;
    float cos_t = c / sqrtf(n2);
    float sin_t = sqrtf((a * a + bb * bb) / n2);
    float sab = sqrtf(a * a + bb * bb);
    float u1 = bb / sab, u2 = -a / sab;
    const float r0 = -u2 * sin_t, r1 = u1 * sin_t, r2 = cos_t, tz = d / c;

    double sz = 0.0; int ic = 0; float zmx = -INFINITY, zmn = -INFINITY;  // zmn = max(-zc)
#pragma unroll
    for (int h = 0; h < 2; ++h) {
      if (h == 1 && !has2) break;
      float4 q = sPts[t + h * 256];
      // identical per-lane chain to phase-2 pk_fma halves
      float dist = fmaf(q.x, a, fmaf(q.y, bb, fmaf(q.z, c, d)));
      if (fabsf(dist) <= th) {
        float zc = fmaf(q.x, r0, fmaf(q.y, r1, (q.z + tz) * r2));
        sz += (double)zc; ic++;
        zmx = fmaxf(zmx, zc);
        zmn = fmaxf(zmn, -zc);
      }
    }
    for (int o = 32; o; o >>= 1) {
      sz += __shfl_down(sz, o); ic += __shfl_down(ic, o);
      zmx = fmaxf(zmx, __shfl_down(zmx, o));
      zmn = fmaxf(zmn, __shfl_down(zmn, o));
    }
    if (lane == 0) { sD0[wid] = sz; sI0[wid] = ic; sF0[wid] = zmx; sF1s[wid] = zmn; }
    __syncthreads();
    if (t == 0) {
      unsigned long long* e = zp + (size_t)b * 3;
      ast64(e + 0, __double_as_longlong(sD0[0]+sD0[1]+sD0[2]+sD0[3]));
      ast64(e + 1, (unsigned long long)(sI0[0]+sI0[1]+sI0[2]+sI0[3]));
      float bmx = fmaxf(fmaxf(sF0[0], sF0[1]), fmaxf(sF0[2], sF0[3]));
      float bmn = fmaxf(fmaxf(sF1s[0], sF1s[1]), fmaxf(sF1s[2], sF1s[3]));
      ast64(e + 2, (unsigned long long)__float_as_uint(bmx) |
                   ((unsigned long long)__float_as_uint(bmn) << 32));
    }
    __syncthreads();   // drain vmcnt
    if (t == 0)
      sU = __hip_atomic_fetch_add(wC3, 1u, __ATOMIC_ACQ_REL, __HIP_MEMORY_SCOPE_AGENT);
    __syncthreads();
    if (sU != kPoison + (unsigned)(kB - 1)) return;

    // ---- final: reduce zc partials, pmdg, outputs ----
    double gs = 0.0; int gi = 0; float gmx = -INFINITY, gmn = -INFINITY;
    for (int r = t; r < kB; r += 256) {
      const unsigned long long* e = zp + (size_t)r * 3;
      gs += __longlong_as_double(ald64(e + 0));
      gi += (int)ald64(e + 1);
      unsigned long long mm = ald64(e + 2);
      gmx = fmaxf(gmx, __uint_as_float((unsigned)(mm & 0xFFFFFFFFu)));
      gmn = fmaxf(gmn, __uint_as_float((unsigned)(mm >> 32)));
    }
    for (int o = 32; o; o >>= 1) {
      gs += __shfl_down(gs, o); gi += __shfl_down(gi, o);
      gmx = fmaxf(gmx, __shfl_down(gmx, o));
      gmn = fmaxf(gmn, __shfl_down(gmn, o));
    }
    if (lane == 0) { sD0[wid] = gs; sI0[wid] = gi; sF0[wid] = gmx; sF1s[wid] = gmn; }
    __syncthreads();
    if (t == 0) {
      double S = sD0[0]+sD0[1]+sD0[2]+sD0[3];
      int IC = sI0[0]+sI0[1]+sI0[2]+sI0[3];
      float MX = fmaxf(fmaxf(sF0[0], sF0[1]), fmaxf(sF0[2], sF0[3]));
      float MN = fmaxf(fmaxf(sF1s[0], sF1s[1]), fmaxf(sF1s[2], sF1s[3]));
      double below = 0.0, above = 0.0;
      if (IC > 0) {
        double icd = (double)IC;
        double mean = S / icd;
        below = (double)MX - mean;    // sum(|zc - zmax|)/icnt  (all zc <= zmax)
        above = mean - (double)(-MN); // sum(|zc - zmin|)/icnt
      }
      if (above == 0.0) above = 1e-7;
      double pmdg = 1000.0 * (above + below);
      double loss17 = __longlong_as_double(ald64(wL17));
      out[4] = (float)pmdg;
      out[6] = (float)(loss17 + pmdg);
    }
  }
}

}  // namespace

extern "C" void kernel_launch(void* const* d_in, const int* in_sizes, int n_in,
                              void* d_out, int out_size, void* d_ws, size_t ws_size,
                              hipStream_t stream) {
  (void)in_sizes; (void)n_in; (void)out_size; (void)ws_size;
  const float* fake = (const float*)d_in[0];
  const float* real = (const float*)d_in[1];
  const int* epoch = (const int*)d_in[2];
  float* out = (float*)d_out;
  char* ws = (char*)d_ws;

  void* args[] = { (void*)&fake, (void*)&real, (void*)&epoch, (void*)&out, (void*)&ws };
  hipLaunchCooperativeKernel(reinterpret_cast<void*>(&k_all),
                             dim3(kB), dim3(256), args, 0, stream);
}

// Round 7
// 156.060 us; speedup vs baseline: 1.6447x; 1.6447x over previous
//
#include <hip/hip_runtime.h>

namespace {

typedef float v2f __attribute__((ext_vector_type(2)));

constexpr int kW = 640;
constexpr unsigned kSpan = 230400u;   // 360*640
constexpr int kB1 = 900;              // K1 blocks (256 pts each)
constexpr int kB2 = 512;              // K2 blocks (450 pts each)
constexpr int kPPB2 = 450;
constexpr int kTail = 16;             // select/zc tail blocks in K2
constexpr int kSlice = 230400 / kTail;   // 14400 pts per tail block
constexpr unsigned kPoison = 0xAAAAAAAAu;

// ws offsets (bytes); ws is poisoned 0xAA before every run
constexpr size_t kOffMaxv   = 0;      // u64: f32 bits of maxv   (written by K1 tail)
constexpr size_t kOffL17    = 8;      // u64: double bits of loss17
constexpr size_t kOffSel    = 16;     // u32: selkey atomicMax target (init 0 by K1 tail)
constexpr size_t kOffC1     = 128;    // K1 arrival counter (poison-based)
constexpr size_t kOffC2     = 192;    // K2 count arrival counter
constexpr size_t kOffC2b    = 256;    // K2 select-done counter
constexpr size_t kOffC3     = 320;    // K2 zc arrival counter
constexpr size_t kOffPlanes = 512;    // 1024 * 16 = 16384
constexpr size_t kOffSP     = 17408;  // 900 * 48 = 43200 (ends 60608)
constexpr size_t kOffZP     = 60928;  // 16 * 32 = 512
constexpr size_t kOffPart   = 65536;  // 512 * 256 * 8 = 1 MB

__device__ __forceinline__ void ast64(unsigned long long* p, unsigned long long v) {
  __hip_atomic_store(p, v, __ATOMIC_RELAXED, __HIP_MEMORY_SCOPE_AGENT);
}
__device__ __forceinline__ unsigned long long ald64(const unsigned long long* p) {
  return __hip_atomic_load(p, __ATOMIC_RELAXED, __HIP_MEMORY_SCOPE_AGENT);
}
__device__ __forceinline__ void ast32(unsigned* p, unsigned v) {
  __hip_atomic_store(p, v, __ATOMIC_RELAXED, __HIP_MEMORY_SCOPE_AGENT);
}
__device__ __forceinline__ unsigned ald32(const unsigned* p) {
  return __hip_atomic_load(p, __ATOMIC_RELAXED, __HIP_MEMORY_SCOPE_AGENT);
}

__device__ __forceinline__ unsigned rotl32(unsigned v, int r) {
  return (v << r) | (v >> (32 - r));
}

// Threefry-2x32, 20 rounds, key = (0, 42)  [jax.random.key(42)]
__device__ __forceinline__ void threefry(unsigned c0, unsigned c1,
                                         unsigned& o0, unsigned& o1) {
  const unsigned ks0 = 0u, ks1 = 42u, ks2 = 0x1BD11BDAu ^ 0u ^ 42u;
  unsigned x0 = c0 + ks0, x1 = c1 + ks1;
#define TFR(r) { x0 += x1; x1 = rotl32(x1, (r)); x1 ^= x0; }
  TFR(13) TFR(15) TFR(26) TFR(6)
  x0 += ks1; x1 += ks2 + 1u;
  TFR(17) TFR(29) TFR(16) TFR(24)
  x0 += ks2; x1 += ks0 + 2u;
  TFR(13) TFR(15) TFR(26) TFR(6)
  x0 += ks0; x1 += ks1 + 3u;
  TFR(17) TFR(29) TFR(16) TFR(24)
  x0 += ks1; x1 += ks2 + 4u;
  TFR(13) TFR(15) TFR(26) TFR(6)
  x0 += ks2; x1 += ks0 + 5u;
#undef TFR
  o0 = x0; o1 = x1;
}

__device__ __forceinline__ void pix_coords(float d, int row, int col, bool& valid,
                                           float& x, float& y, float& z) {
  valid = (d > 0.0f) && (d < 65535.0f);
  float z0 = d / 1000.0f;
  float x0 = z0 * ((float)col - 334.081f) / 460.585f;
  float y0 = z0 * ((float)row - 169.808f) / 460.268f;
  x = x0 * 1000.0f;
  y = y0 * 1000.0f;
  z = z0 * 1000.0f;
  if (x == 0.0f) x = 1e-7f;
  if (y == 0.0f) y = 1e-7f;
  if (z == 0.0f) z = 1e-7f;
}

// normalized point — identical expression wherever used (bitwise mask consistency)
__device__ __forceinline__ void make_pt(float d, int row, int col, float maxv,
                                        float& x, float& y, float& z) {
  bool v; float a, b, c;
  pix_coords(d, row, col, v, a, b, c);
  x = (v ? a : 0.f) / maxv;
  y = (v ? b : 0.f) / maxv;
  z = (v ? c : 0.f) / maxv;
}

__device__ __forceinline__ float get_thresh(int ep) {
  return (float)fmax(0.025 - 0.001 * (double)ep, 0.005);
}

// ================= K1: stats partials; last block reduces, scalars, planes =================
__global__ __launch_bounds__(256) void k_stats(const float* __restrict__ fake,
                                               const float* __restrict__ real,
                                               float* __restrict__ out,
                                               char* __restrict__ ws) {
  unsigned long long* wMaxv = (unsigned long long*)(ws + kOffMaxv);
  unsigned long long* wL17 = (unsigned long long*)(ws + kOffL17);
  unsigned* wSel = (unsigned*)(ws + kOffSel);
  unsigned* ctr = (unsigned*)(ws + kOffC1);
  float4* planes = (float4*)(ws + kOffPlanes);
  unsigned long long* sp = (unsigned long long*)(ws + kOffSP);

  const int b = blockIdx.x, t = threadIdx.x;
  const int lane = t & 63, wid = t >> 6;

  __shared__ double sD0[4], sD1[4], sD2[4], sD3[4];
  __shared__ int sI0[4];
  __shared__ float sF0[4];
  __shared__ unsigned sArr;
  __shared__ float sMaxv;

  {
    int i = b * 256 + t;
    int row = i / kW, col = i - row * kW;
    bool vr, vf; float rx, ry, rz, fx, fy, fz;
    pix_coords(real[i], row, col, vr, rx, ry, rz);
    pix_coords(fake[i], row, col, vf, fx, fy, fz);
    double dx2 = 0, dy2 = 0, dz2 = 0, dl2 = 0; int cc = 0;
    if (vr && vf) {
      float ddx = rx - fx, ddy = ry - fy, ddz = rz - fz;
      dx2 = (double)ddx * (double)ddx;
      dy2 = (double)ddy * (double)ddy;
      dz2 = (double)ddz * (double)ddz;
      double dl = log(fabs((double)rz)) - log(fabs((double)fz));
      dl2 = dl * dl;
      cc = 1;
    }
    float mx = vf ? fmaxf(fmaxf(fx, fy), fz) : 0.0f;
    for (int o = 32; o; o >>= 1) {
      dx2 += __shfl_down(dx2, o); dy2 += __shfl_down(dy2, o);
      dz2 += __shfl_down(dz2, o); dl2 += __shfl_down(dl2, o);
      cc += __shfl_down(cc, o);
      mx = fmaxf(mx, __shfl_down(mx, o));
    }
    if (lane == 0) { sD0[wid]=dx2; sD1[wid]=dy2; sD2[wid]=dz2; sD3[wid]=dl2;
                     sI0[wid]=cc; sF0[wid]=mx; }
    __syncthreads();
    if (t == 0) {
      unsigned long long* e = sp + (size_t)b * 6;
      ast64(e + 0, __double_as_longlong(sD0[0]+sD0[1]+sD0[2]+sD0[3]));
      ast64(e + 1, __double_as_longlong(sD1[0]+sD1[1]+sD1[2]+sD1[3]));
      ast64(e + 2, __double_as_longlong(sD2[0]+sD2[1]+sD2[2]+sD2[3]));
      ast64(e + 3, __double_as_longlong(sD3[0]+sD3[1]+sD3[2]+sD3[3]));
      ast64(e + 4, (unsigned long long)(sI0[0]+sI0[1]+sI0[2]+sI0[3]));
      float bm = fmaxf(fmaxf(sF0[0], sF0[1]), fmaxf(sF0[2], sF0[3]));
      ast64(e + 5, (unsigned long long)__float_as_uint(bm));
    }
  }
  __syncthreads();
  if (t == 0)
    sArr = __hip_atomic_fetch_add(ctr, 1u, __ATOMIC_ACQ_REL, __HIP_MEMORY_SCOPE_AGENT);
  __syncthreads();
  if (sArr != kPoison + (unsigned)(kB1 - 1)) return;   // only last arrival continues

  // ---- tail: global reduce + scalar losses + plane build ----
  {
    double gx = 0, gy = 0, gz = 0, gl = 0; int gc = 0; float gm = 0.f;
    for (int r = t; r < kB1; r += 256) {
      const unsigned long long* e = sp + (size_t)r * 6;
      gx += __longlong_as_double(ald64(e + 0));
      gy += __longlong_as_double(ald64(e + 1));
      gz += __longlong_as_double(ald64(e + 2));
      gl += __longlong_as_double(ald64(e + 3));
      gc += (int)ald64(e + 4);
      gm = fmaxf(gm, __uint_as_float((unsigned)ald64(e + 5)));
    }
    for (int o = 32; o; o >>= 1) {
      gx += __shfl_down(gx, o); gy += __shfl_down(gy, o);
      gz += __shfl_down(gz, o); gl += __shfl_down(gl, o);
      gc += __shfl_down(gc, o);
      gm = fmaxf(gm, __shfl_down(gm, o));
    }
    if (lane == 0) { sD0[wid]=gx; sD1[wid]=gy; sD2[wid]=gz; sD3[wid]=gl;
                     sI0[wid]=gc; sF0[wid]=gm; }
    __syncthreads();
    if (t == 0) {
      double SX = sD0[0]+sD0[1]+sD0[2]+sD0[3];
      double SY = sD1[0]+sD1[1]+sD1[2]+sD1[3];
      double SZ = sD2[0]+sD2[1]+sD2[2]+sD2[3];
      double SL = sD3[0]+sD3[1]+sD3[2]+sD3[3];
      int CN = sI0[0]+sI0[1]+sI0[2]+sI0[3];
      float MX = fmaxf(fmaxf(sF0[0], sF0[1]), fmaxf(sF0[2], sF0[3]));
      double cntd = (CN > 0) ? (double)CN : 1.0;
      double lossX = sqrt(SX / cntd);
      double lossY = sqrt(SY / cntd);
      double lossZ = sqrt(SZ / cntd);
      double rmse_log = 10000.0 * sqrt(SL / cntd);
      double loss17 = rmse_log * fabs(10.0 * (3.0 - exp(lossX) - exp(lossY) - exp(lossZ)));
      out[0] = (float)rmse_log;
      out[1] = (float)lossX;
      out[2] = (float)lossY;
      out[3] = (float)lossZ;
      out[5] = (float)loss17;
      ast64(wMaxv, (unsigned long long)__float_as_uint(MX));
      ast64(wL17, __double_as_longlong(loss17));
      ast32(wSel, 0u);                       // init atomicMax target (overwrite poison)
      sMaxv = MX;
    }
    __syncthreads();
  }
  {
    float maxv = sMaxv;
#pragma unroll
    for (int j = 0; j < 4; j++) {
      int pid = t * 4 + j;                   // 0..1023
      float4 pl;
      if (pid < 1000) {
        float px[3], py[3], pz[3];
#pragma unroll
        for (int v = 0; v < 3; v++) {
          unsigned p = 3u * (unsigned)pid + (unsigned)v;
          unsigned o0, o1;
          threefry(p, p + 3000u, o0, o1);    // JAX randint: multiplier wraps to 0 => o1 % span
          unsigned idx = o1 % kSpan;
          int row = (int)(idx / kW), col = (int)idx - row * kW;
          make_pt(fake[idx], row, col, maxv, px[v], py[v], pz[v]);
        }
        float ax = px[1]-px[0], ay = py[1]-py[0], az = pz[1]-pz[0];
        float bx = px[2]-px[0], by = py[2]-py[0], bz = pz[2]-pz[0];
        float nx = ay*bz - az*by;
        float ny = az*bx - ax*bz;
        float nz = ax*by - ay*bx;
        float nn = sqrtf(nx*nx + ny*ny + nz*nz);
        nx /= nn; ny /= nn; nz /= nn;
        float kk = -(nx*px[1] + ny*py[1] + nz*pz[1]);
        pl = make_float4(nx, ny, nz, kk);
      } else {
        pl = make_float4(0.f, 0.f, 0.f, 3e38f);   // dummy: never an inlier
      }
      planes[pid] = pl;   // plain store; consumed by next kernel (stream order)
    }
  }
}

// ====== K2: count (all blocks) -> select -> zc -> final (chained last-16 tail) ======
__global__ __launch_bounds__(256) void k_count(const float* __restrict__ fake,
                                               const int* __restrict__ epoch,
                                               float* __restrict__ out,
                                               char* __restrict__ ws) {
  const unsigned long long* wMaxv = (const unsigned long long*)(ws + kOffMaxv);
  const unsigned long long* wL17 = (const unsigned long long*)(ws + kOffL17);
  unsigned* wSel = (unsigned*)(ws + kOffSel);
  unsigned* wC2 = (unsigned*)(ws + kOffC2);
  unsigned* wC2b = (unsigned*)(ws + kOffC2b);
  unsigned* wC3 = (unsigned*)(ws + kOffC3);
  const float4* planes = (const float4*)(ws + kOffPlanes);
  unsigned long long* zp = (unsigned long long*)(ws + kOffZP);
  unsigned long long* part = (unsigned long long*)(ws + kOffPart);

  const int b = blockIdx.x, t = threadIdx.x;
  const int lane = t & 63, wid = t >> 6;
  const float th = get_thresh(*epoch);
  const float maxv = __uint_as_float((unsigned)*wMaxv);

  __shared__ float4 sPts[kPPB2];
  __shared__ uint4 sAcc[16][16];
  __shared__ double sD0[4];
  __shared__ int sI0[4];
  __shared__ float sF0[4], sF1[4];
  __shared__ unsigned sArr;

  // ---- stage my 450 normalized points into LDS (recomputed; bit-identical) ----
  {
    int i = b * kPPB2 + t;
    int row = i / kW, col = i - row * kW;
    float x, y, z;
    make_pt(fake[i], row, col, maxv, x, y, z);
    sPts[t] = make_float4(x, y, z, 0.f);
    if (t < kPPB2 - 256) {
      int i2 = i + 256;
      int row2 = i2 / kW, col2 = i2 - row2 * kW;
      make_pt(fake[i2], row2, col2, maxv, x, y, z);
      sPts[t + 256] = make_float4(x, y, z, 0.f);
    }
  }
  // each lane owns 4 planes in registers
  float4 p0 = planes[t * 4 + 0], p1 = planes[t * 4 + 1];
  float4 p2 = planes[t * 4 + 2], p3 = planes[t * 4 + 3];
  v2f Ax = {p0.x, p1.x}, Ay = {p0.y, p1.y}, Az = {p0.z, p1.z}, Aw = {p0.w, p1.w};
  v2f Bx = {p2.x, p3.x}, By = {p2.y, p3.y}, Bz = {p2.z, p3.z}, Bw = {p2.w, p3.w};
  __syncthreads();

  unsigned c0 = 0, c1 = 0, c2 = 0, c3 = 0;
#pragma unroll 6
  for (int s = 0; s < kPPB2; ++s) {
    float4 q = sPts[s];                    // broadcast ds_read_b128
    v2f qx = {q.x, q.x}, qy = {q.y, q.y}, qz = {q.z, q.z};
    // per-half chain == fmaf(qx,a,fmaf(qy,b,fmaf(qz,c,d))) — matches zc scalar chain
    v2f dA = __builtin_elementwise_fma(qx, Ax,
             __builtin_elementwise_fma(qy, Ay,
             __builtin_elementwise_fma(qz, Az, Aw)));
    v2f dB = __builtin_elementwise_fma(qx, Bx,
             __builtin_elementwise_fma(qy, By,
             __builtin_elementwise_fma(qz, Bz, Bw)));
    c0 += (fabsf(dA.x) <= th) ? 1u : 0u;
    c1 += (fabsf(dA.y) <= th) ? 1u : 0u;
    c2 += (fabsf(dB.x) <= th) ? 1u : 0u;
    c3 += (fabsf(dB.y) <= th) ? 1u : 0u;
  }
  ast64(&part[(size_t)b * 256 + t],
        ((unsigned long long)(c0 | (c1 << 16))) |
        ((unsigned long long)(c2 | (c3 << 16)) << 32));
  __syncthreads();   // drains vmcnt: packed count stores globally performed
  if (t == 0)
    sArr = __hip_atomic_fetch_add(wC2, 1u, __ATOMIC_ACQ_REL, __HIP_MEMORY_SCOPE_AGENT);
  __syncthreads();
  unsigned ret = sArr;
  if (ret < kPoison + (unsigned)(kB2 - kTail)) return;   // 496 blocks exit here
  const int r = (int)(ret - (kPoison + (unsigned)(kB2 - kTail)));  // 0..15

  // ---- distributed select among the last-16 (co-arrived) blocks ----
  if (t == 0) {
    while (__hip_atomic_load(wC2, __ATOMIC_ACQUIRE, __HIP_MEMORY_SCOPE_AGENT)
           != kPoison + (unsigned)kB2)
      __builtin_amdgcn_s_sleep(2);
  }
  __syncthreads();
  {
    int owner = r * 16 + (t & 15);        // owner column 0..255
    int chunk = t >> 4;                   // 16 chunks x 32 rows = 512 rows
    unsigned s0 = 0, s1 = 0, s2 = 0, s3 = 0;
    for (int row = chunk * 32; row < chunk * 32 + 32; ++row) {
      unsigned long long v = ald64(&part[(size_t)row * 256 + owner]);
      s0 += (unsigned)(v & 0xFFFFu);
      s1 += (unsigned)((v >> 16) & 0xFFFFu);
      s2 += (unsigned)((v >> 32) & 0xFFFFu);
      s3 += (unsigned)(v >> 48);
    }
    sAcc[t & 15][chunk] = make_uint4(s0, s1, s2, s3);
  }
  __syncthreads();
  {
    unsigned mykey = 0u;
    if (t < 16) {
      unsigned t0 = 0, t1 = 0, t2 = 0, t3 = 0;
      for (int j = 0; j < 16; ++j) {
        uint4 v = sAcc[t][j];
        t0 += v.x; t1 += v.y; t2 += v.z; t3 += v.w;
      }
      unsigned tot[4] = {t0, t1, t2, t3};
      int pbase = (r * 16 + t) * 4;
#pragma unroll
      for (int k = 0; k < 4; ++k) {
        int p = pbase + k;
        int score = ((int)tot[k] > 5000) ? (int)tot[k] : -1;   // MIN_POINTS, strict >
        unsigned key = ((unsigned)(score + 2) << 10) | (unsigned)(1023 - p);
        mykey = key > mykey ? key : mykey;
      }
    }
    for (int o = 32; o; o >>= 1) {
      unsigned other = __shfl_down(mykey, o);
      mykey = other > mykey ? other : mykey;
    }
    if (t == 0) {
      atomicMax(wSel, mykey);
      __hip_atomic_fetch_add(wC2b, 1u, __ATOMIC_RELEASE, __HIP_MEMORY_SCOPE_AGENT);
      // wait for all 16 selections (co-arrived blocks; ~µs)
      while (__hip_atomic_load(wC2b, __ATOMIC_ACQUIRE, __HIP_MEMORY_SCOPE_AGENT)
             != kPoison + (unsigned)kTail)
        __builtin_amdgcn_s_sleep(2);
      sArr = __hip_atomic_load(wSel, __ATOMIC_RELAXED, __HIP_MEMORY_SCOPE_AGENT);
    }
  }
  __syncthreads();

  // ---- zc over my 1/16 slice of all points (recomputed, bit-identical) ----
  {
    int best = 1023 - (int)(sArr & 1023u);
    float4 pl = planes[best];
    const float a = pl.x, bb = pl.y, c = pl.z, d = pl.w;
    float n2 = a * a + bb * bb + c * c;
    float cos_t = c / sqrtf(n2);
    float sin_t = sqrtf((a * a + bb * bb) / n2);
    float sab = sqrtf(a * a + bb * bb);
    float u1 = bb / sab, u2 = -a / sab;
    const float r0 = -u2 * sin_t, r1 = u1 * sin_t, r2 = cos_t, tz = d / c;

    double sz = 0.0; int ic = 0; float zmx = -INFINITY, zmn = -INFINITY; // zmn=max(-zc)
    for (int k = t; k < kSlice; k += 256) {
      int i = r * kSlice + k;
      int row = i / kW, col = i - row * kW;
      float qx, qy, qz;
      make_pt(fake[i], row, col, maxv, qx, qy, qz);
      // identical per-lane chain to the count pk_fma halves
      float dist = fmaf(qx, a, fmaf(qy, bb, fmaf(qz, c, d)));
      if (fabsf(dist) <= th) {
        float zc = fmaf(qx, r0, fmaf(qy, r1, (qz + tz) * r2));
        sz += (double)zc; ic++;
        zmx = fmaxf(zmx, zc);
        zmn = fmaxf(zmn, -zc);
      }
    }
    for (int o = 32; o; o >>= 1) {
      sz += __shfl_down(sz, o); ic += __shfl_down(ic, o);
      zmx = fmaxf(zmx, __shfl_down(zmx, o));
      zmn = fmaxf(zmn, __shfl_down(zmn, o));
    }
    if (lane == 0) { sD0[wid] = sz; sI0[wid] = ic; sF0[wid] = zmx; sF1[wid] = zmn; }
    __syncthreads();
    if (t == 0) {
      unsigned long long* e = zp + (size_t)r * 4;
      ast64(e + 0, __double_as_longlong(sD0[0]+sD0[1]+sD0[2]+sD0[3]));
      ast64(e + 1, (unsigned long long)(sI0[0]+sI0[1]+sI0[2]+sI0[3]));
      float bmx = fmaxf(fmaxf(sF0[0], sF0[1]), fmaxf(sF0[2], sF0[3]));
      float bmn = fmaxf(fmaxf(sF1[0], sF1[1]), fmaxf(sF1[2], sF1[3]));
      ast64(e + 2, (unsigned long long)__float_as_uint(bmx) |
                   ((unsigned long long)__float_as_uint(bmn) << 32));
    }
    __syncthreads();   // drains vmcnt
    if (t == 0)
      sArr = __hip_atomic_fetch_add(wC3, 1u, __ATOMIC_ACQ_REL, __HIP_MEMORY_SCOPE_AGENT);
    __syncthreads();
    if (sArr != kPoison + (unsigned)(kTail - 1)) return;
  }

  // ---- final: reduce 16 zc partials, pmdg, outputs (first wave only) ----
  if (t < 64) {
    double gs = 0.0; int gi = 0; float gmx = -INFINITY, gmn = -INFINITY;
    if (t < kTail) {
      const unsigned long long* e = zp + (size_t)t * 4;
      gs = __longlong_as_double(ald64(e + 0));
      gi = (int)ald64(e + 1);
      unsigned long long mm = ald64(e + 2);
      gmx = __uint_as_float((unsigned)(mm & 0xFFFFFFFFu));
      gmn = __uint_as_float((unsigned)(mm >> 32));
    }
    for (int o = 8; o; o >>= 1) {
      gs += __shfl_down(gs, o); gi += __shfl_down(gi, o);
      gmx = fmaxf(gmx, __shfl_down(gmx, o));
      gmn = fmaxf(gmn, __shfl_down(gmn, o));
    }
    if (t == 0) {
      double below = 0.0, above = 0.0;
      if (gi > 0) {
        double icd = (double)gi;
        double mean = gs / icd;
        below = (double)gmx - mean;    // sum(|zc - zmax|)/icnt  (all zc <= zmax)
        above = mean - (double)(-gmn); // sum(|zc - zmin|)/icnt
      }
      if (above == 0.0) above = 1e-7;
      double pmdg = 1000.0 * (above + below);
      double loss17 = __longlong_as_double(*wL17);
      out[4] = (float)pmdg;
      out[6] = (float)(loss17 + pmdg);
    }
  }
}

}  // namespace

extern "C" void kernel_launch(void* const* d_in, const int* in_sizes, int n_in,
                              void* d_out, int out_size, void* d_ws, size_t ws_size,
                              hipStream_t stream) {
  (void)in_sizes; (void)n_in; (void)out_size; (void)ws_size;
  const float* fake = (const float*)d_in[0];
  const float* real = (const float*)d_in[1];
  const int* epoch = (const int*)d_in[2];
  float* out = (float*)d_out;
  char* ws = (char*)d_ws;

  k_stats<<<kB1, 256, 0, stream>>>(fake, real, out, ws);
  k_count<<<kB2, 256, 0, stream>>>(fake, epoch, out, ws);
}